// Round 6
// baseline (158.673 us; speedup 1.0000x reference)
//
#include <hip/hip_runtime.h>

typedef unsigned int  u32;
typedef unsigned short u16;

typedef __bf16 bf16x8 __attribute__((ext_vector_type(8)));
typedef u32    u32x4  __attribute__((ext_vector_type(4)));
typedef float  floatx4 __attribute__((ext_vector_type(4)));

#define N_ROWS 256
#define IN_F   8192
#define OUT_F  8320
#define JDIM   128
#define KDIM   16
#define JK     2048

#define BN      64
#define KSLAB   512
#define NSLAB   16

__device__ __forceinline__ u16 f2bf(float f) {
    u32 u = __float_as_uint(f);
    return (u16)((u + 0x7fffu + ((u >> 16) & 1u)) >> 16);
}
__device__ __forceinline__ float bf2f(u16 h) { return __uint_as_float(((u32)h) << 16); }

// Kernel A: copy X into out[:, :8192], cvt X->bf16 into Xb, zero diversity region of out.
__global__ __launch_bounds__(256) void prep_kernel(const float* __restrict__ X,
                                                   float* __restrict__ out,
                                                   u16* __restrict__ Xb)
{
    int t = blockIdx.x * 256 + threadIdx.x;      // 0..524287, one float4 each
    float4 v = reinterpret_cast<const float4*>(X)[t];
    int row = t >> 11;
    int c4  = t & 2047;
    reinterpret_cast<float4*>(out + (size_t)row * OUT_F)[c4] = v;
    ushort4 b;
    b.x = f2bf(v.x); b.y = f2bf(v.y); b.z = f2bf(v.z); b.w = f2bf(v.w);
    reinterpret_cast<ushort4*>(Xb)[t] = b;
    if (t < 8192) {
        int r2 = t >> 5, j4 = t & 31;
        reinterpret_cast<float4*>(out + (size_t)r2 * OUT_F + IN_F)[j4] = make_float4(0.f, 0.f, 0.f, 0.f);
    }
}

// Kernel B: slab[s] = Xb[256 rows, 512k] * W[512k, 64 cols]. ZERO LDS, ZERO barriers.
// B-frags loaded DIRECTLY from k-major fp32 W: lane (n=lane&15, q=lane>>4) needs
// W[k0+q*8+j][col+n], j=0..7 -> 8 dword loads, coalesced 64B per quad, block covers a
// contiguous 256B col-stripe per k-row => W read exactly once, full line utilization.
// fp32->bf16 by truncation in registers (precision slack: exp(-l1)=0 off-diag, diag exact).
// A-frags: 16B contiguous loads from L2-resident Xb. Both operands 1-deep double-buffered.
// Wave = 128 rows x 32 cols. Grid (32 col-blocks, 16 slabs) = 512 blocks.
__global__ __launch_bounds__(256) void gemm_kernel(const u16* __restrict__ Xb,
                                                   const float* __restrict__ W,
                                                   u16* __restrict__ slabs)
{
    const int tid  = threadIdx.x;
    const int lane = tid & 63;
    const int wave = tid >> 6;
    const int c0   = blockIdx.x * BN;
    const int s    = blockIdx.y;
    const int k0   = s * KSLAB;

    const int h  = wave >> 1;            // row half: rows h*128 .. +127
    const int cc = wave & 1;             // col half: cols cc*32 .. +31
    const int n  = lane & 15;
    const int q  = lane >> 4;

    floatx4 acc[8][2] = {};              // [row-frag][col-frag]

    const u32* wbase = (const u32*)W + (size_t)(k0 + q * 8) * JK + c0 + cc * 32 + n;
    const u16* abase = Xb + k0 + q * 8;

    u32 ub[2][8], ubn[2][8];
    bf16x8 a[8], an[8];

    // prologue: load kc=0 operands
    #pragma unroll
    for (int cbi = 0; cbi < 2; ++cbi)
        #pragma unroll
        for (int j = 0; j < 8; ++j)
            ub[cbi][j] = wbase[(size_t)j * JK + cbi * 16];
    #pragma unroll
    for (int rf = 0; rf < 8; ++rf)
        a[rf] = *(const bf16x8*)(abase + (size_t)(h * 128 + rf * 16 + n) * IN_F);

    const int KC = KSLAB / 32;           // 16
    for (int kc = 0; kc < KC; ++kc) {
        // prefetch next iter's operands first; they stay in flight across the MFMAs
        if (kc + 1 < KC) {
            const u32* wp = wbase + (size_t)(kc + 1) * 32 * JK;
            #pragma unroll
            for (int cbi = 0; cbi < 2; ++cbi)
                #pragma unroll
                for (int j = 0; j < 8; ++j)
                    ubn[cbi][j] = wp[(size_t)j * JK + cbi * 16];
            #pragma unroll
            for (int rf = 0; rf < 8; ++rf)
                an[rf] = *(const bf16x8*)(abase + (size_t)(h * 128 + rf * 16 + n) * IN_F + (kc + 1) * 32);
        }

        // pack current B dwords -> bf16 frags (truncation: high halves)
        bf16x8 b[2];
        #pragma unroll
        for (int cbi = 0; cbi < 2; ++cbi) {
            u32x4 pk;
            #pragma unroll
            for (int t = 0; t < 4; ++t)
                pk[t] = (ub[cbi][2 * t] >> 16) | (ub[cbi][2 * t + 1] & 0xffff0000u);
            b[cbi] = __builtin_bit_cast(bf16x8, pk);
        }

        #pragma unroll
        for (int rf = 0; rf < 8; ++rf)
            #pragma unroll
            for (int cbi = 0; cbi < 2; ++cbi)
                acc[rf][cbi] = __builtin_amdgcn_mfma_f32_16x16x32_bf16(a[rf], b[cbi], acc[rf][cbi], 0, 0, 0);

        #pragma unroll
        for (int cbi = 0; cbi < 2; ++cbi)
            #pragma unroll
            for (int j = 0; j < 8; ++j)
                ub[cbi][j] = ubn[cbi][j];
        #pragma unroll
        for (int rf = 0; rf < 8; ++rf)
            a[rf] = an[rf];
    }

    // epilogue: bf16 stores. D: col=lane&15, row=(lane>>4)*4+reg
    u16* sp = slabs + (size_t)s * N_ROWS * JK;
    #pragma unroll
    for (int rf = 0; rf < 8; ++rf)
        #pragma unroll
        for (int cbi = 0; cbi < 2; ++cbi)
            #pragma unroll
            for (int r = 0; r < 4; ++r) {
                int row = h * 128 + rf * 16 + q * 4 + r;
                int col = c0 + cc * 32 + cbi * 16 + n;
                sp[(size_t)row * JK + col] = f2bf(acc[rf][cbi][r]);
            }
}

// Kernel C: feats[n,jk] = sum_s slab[s][n,jk] (bf16 -> fp32).
__global__ __launch_bounds__(256) void reduce_kernel(const u16* __restrict__ slabs,
                                                     float* __restrict__ feats)
{
    int t = blockIdx.x * 256 + threadIdx.x;      // 65536 threads x 8 elems
    float acc[8] = {};
    for (int s = 0; s < NSLAB; ++s) {
        uint4 v = *(const uint4*)(slabs + (size_t)s * N_ROWS * JK + (size_t)t * 8);
        const u16* h = (const u16*)&v;
        #pragma unroll
        for (int e = 0; e < 8; ++e) acc[e] += bf2f(h[e]);
    }
    float4* fp = (float4*)(feats + (size_t)t * 8);
    fp[0] = make_float4(acc[0], acc[1], acc[2], acc[3]);
    fp[1] = make_float4(acc[4], acc[5], acc[6], acc[7]);
}

// Kernel D: diversity[n,j] = sum_m exp(-sum_k |feats[n,j,k]-feats[m,j,k]|), m-chunked.
__global__ __launch_bounds__(256) void pairwise_kernel(const float* __restrict__ feats,
                                                       float* __restrict__ out)
{
    const int j = blockIdx.x;              // 0..127
    const int mq = blockIdx.y;             // 0..3 -> m chunk of 64
    const int n = threadIdx.x;

    __shared__ float F[N_ROWS * KDIM];     // 16 KB
    const float* fr = feats + (size_t)n * JK + j * KDIM;
    float4 v0 = ((const float4*)fr)[0];
    float4 v1 = ((const float4*)fr)[1];
    float4 v2 = ((const float4*)fr)[2];
    float4 v3 = ((const float4*)fr)[3];
    float4* Fp = (float4*)&F[n * KDIM];
    Fp[0] = v0; Fp[1] = v1; Fp[2] = v2; Fp[3] = v3;
    __syncthreads();

    float f[16] = { v0.x, v0.y, v0.z, v0.w, v1.x, v1.y, v1.z, v1.w,
                    v2.x, v2.y, v2.z, v2.w, v3.x, v3.y, v3.z, v3.w };
    float accum = 0.f;
    const int m0 = mq * 64;
    for (int m = 0; m < 64; ++m) {
        const float* Fm = &F[(m0 + m) * KDIM];   // wave-uniform -> LDS broadcast
        float l1 = 0.f;
        #pragma unroll
        for (int k = 0; k < 16; ++k) l1 += fabsf(f[k] - Fm[k]);
        accum += exp2f(-1.4426950408889634f * l1);
    }
    atomicAdd(&out[(size_t)n * OUT_F + IN_F + j], accum);
}

extern "C" void kernel_launch(void* const* d_in, const int* in_sizes, int n_in,
                              void* d_out, int out_size, void* d_ws, size_t ws_size,
                              hipStream_t stream)
{
    const float* X = (const float*)d_in[0];   // [256, 8192] fp32
    const float* T = (const float*)d_in[1];   // [8192, 128, 16] fp32 = [8192, 2048]
    float* out = (float*)d_out;               // [256, 8320] fp32

    float* feats = (float*)d_ws;                            // 2 MB fp32 [256,2048]
    u16*   Xb    = (u16*)((char*)d_ws + (2u << 20));        // 4 MB bf16 [256,8192]
    u16*   slabs = (u16*)((char*)d_ws + (6u << 20));        // 16 MB bf16 [16,256,2048]

    prep_kernel<<<2048, 256, 0, stream>>>(X, out, Xb);
    gemm_kernel<<<dim3(JK / BN, NSLAB), 256, 0, stream>>>(Xb, T, slabs);
    reduce_kernel<<<256, 256, 0, stream>>>(slabs, feats);
    pairwise_kernel<<<dim3(JDIM, 4), 256, 0, stream>>>(feats, out);
}

// Round 7
// 151.600 us; speedup vs baseline: 1.0467x; 1.0467x over previous
//
#include <hip/hip_runtime.h>

typedef unsigned int  u32;
typedef unsigned short u16;

typedef __bf16 bf16x8 __attribute__((ext_vector_type(8)));
typedef u32    u32x4  __attribute__((ext_vector_type(4)));
typedef float  floatx4 __attribute__((ext_vector_type(4)));

#define N_ROWS 256
#define IN_F   8192
#define OUT_F  8320
#define JDIM   128
#define KDIM   16
#define JK     2048

#define BN     256          // N-tile: 1KB contiguous read granule per k-row
#define BKC    32           // k per chunk
#define NSLAB  32           // kslab = 256k, 8 chunks
#define PC     257          // LDS row stride in u32 (16 kp-rows per buffer)

__device__ __forceinline__ u16 f2bf(float f) {
    u32 u = __float_as_uint(f);
    return (u16)((u + 0x7fffu + ((u >> 16) & 1u)) >> 16);
}
__device__ __forceinline__ float bf2f(u16 h) { return __uint_as_float(((u32)h) << 16); }

// Kernel A: copy X into out[:, :8192], cvt X->bf16 into Xb, zero diversity region of out.
__global__ __launch_bounds__(256) void prep_kernel(const float* __restrict__ X,
                                                   float* __restrict__ out,
                                                   u16* __restrict__ Xb)
{
    int t = blockIdx.x * 256 + threadIdx.x;      // 0..524287, one float4 each
    float4 v = reinterpret_cast<const float4*>(X)[t];
    int row = t >> 11;
    int c4  = t & 2047;
    reinterpret_cast<float4*>(out + (size_t)row * OUT_F)[c4] = v;
    ushort4 b;
    b.x = f2bf(v.x); b.y = f2bf(v.y); b.z = f2bf(v.z); b.w = f2bf(v.w);
    reinterpret_cast<ushort4*>(Xb)[t] = b;
    if (t < 8192) {
        int r2 = t >> 5, j4 = t & 31;
        reinterpret_cast<float4*>(out + (size_t)r2 * OUT_F + IN_F)[j4] = make_float4(0.f, 0.f, 0.f, 0.f);
    }
}

// Kernel B: slab[s] = Xb[256 rows, 256k] * W[256k, 256 cols].
// READ-GRANULE FIX: block N-tile = 256 cols -> every W k-row is read as a 1KB
// contiguous span (vs 256B before). Staging: per chunk (32k x 256c fp32 = 64KB),
// thread (rp=t>>5, u=t&31) loads rows 2rp,2rp+1 at cols 4u+128j via dwordx4 --
// each wave-instr covers a 512B contiguous segment, full 1KB per row in flight.
// Pack k-pairs -> ds_write_b32 to [kp][c] (stride 257), double-buffered LDS,
// ONE barrier per chunk; W+A prefetch in flight across the MFMA section.
// Wave tile 64r x 128c. Grid (8 N-tiles, 32 kslabs) = 256 blocks x 512 thr.
__global__ __launch_bounds__(512) void gemm_kernel(const u16* __restrict__ Xb,
                                                   const float* __restrict__ W,
                                                   u16* __restrict__ slabs)
{
    __shared__ u32 wt[2 * 16 * PC];     // 2 buffers x 16 kp-rows x 257 = 33 KB

    const int tid  = threadIdx.x;
    const int lane = tid & 63;
    const int w    = tid >> 6;          // wave 0..7
    const int c0   = blockIdx.x * BN;
    const int s    = blockIdx.y;        // kslab
    const int k0   = s * (IN_F / NSLAB);

    const int n  = lane & 15;
    const int q  = lane >> 4;
    const int rp = tid >> 5;            // 0..15 (k-pair row within chunk)
    const int u  = tid & 31;            // col unit

    const int wr0 = (w & 3) * 64;       // wave row base
    const int wc0 = (w >> 2) * 128;     // wave col base (within tile)

    floatx4 acc[4][8] = {};

    // W staging base: rows k0+2rp(+1), cols c0 + 4u (+128j)
    const float* wbase = W + (size_t)(k0 + 2 * rp) * JK + c0 + 4 * u;

    float4 wreg[4];
    wreg[0] = *(const float4*)(wbase);
    wreg[1] = *(const float4*)(wbase + 128);
    wreg[2] = *(const float4*)(wbase + (size_t)JK);
    wreg[3] = *(const float4*)(wbase + (size_t)JK + 128);

    // A-frag base (direct from global, L2/L3-resident)
    const u16* abase = Xb + k0 + q * 8;
    bf16x8 a[4], an[4];
    #pragma unroll
    for (int rf = 0; rf < 4; ++rf)
        a[rf] = *(const bf16x8*)(abase + (size_t)(wr0 + rf * 16 + n) * IN_F);

    // pack & write chunk 0 into buffer 0
    #pragma unroll
    for (int j = 0; j < 2; ++j)
        #pragma unroll
        for (int i = 0; i < 4; ++i) {
            float lo = ((const float*)&wreg[j])[i];        // k = 2rp
            float hi = ((const float*)&wreg[2 + j])[i];    // k = 2rp+1
            wt[rp * PC + 4 * u + 128 * j + i] = (u32)f2bf(lo) | ((u32)f2bf(hi) << 16);
        }
    __syncthreads();

    const int NCH = (IN_F / NSLAB) / BKC;   // 8 chunks
    float4 wnx[4];
    for (int kw = 0; kw < NCH; ++kw) {
        const u32* buf = wt + (kw & 1) * (16 * PC);

        // prefetch next chunk's W + A (stay in flight across MFMAs)
        if (kw + 1 < NCH) {
            const float* wb2 = wbase + (size_t)(kw + 1) * BKC * JK;
            wnx[0] = *(const float4*)(wb2);
            wnx[1] = *(const float4*)(wb2 + 128);
            wnx[2] = *(const float4*)(wb2 + (size_t)JK);
            wnx[3] = *(const float4*)(wb2 + (size_t)JK + 128);
            #pragma unroll
            for (int rf = 0; rf < 4; ++rf)
                an[rf] = *(const bf16x8*)(abase + (size_t)(wr0 + rf * 16 + n) * IN_F + (kw + 1) * BKC);
        }

        // MFMAs on current buffer
        #pragma unroll
        for (int cf = 0; cf < 8; ++cf) {
            int c = wc0 + cf * 16 + n;
            u32x4 bv;
            #pragma unroll
            for (int i = 0; i < 4; ++i)
                bv[i] = buf[(q * 4 + i) * PC + c];
            bf16x8 bfrag = __builtin_bit_cast(bf16x8, bv);
            #pragma unroll
            for (int rf = 0; rf < 4; ++rf)
                acc[rf][cf] = __builtin_amdgcn_mfma_f32_16x16x32_bf16(a[rf], bfrag, acc[rf][cf], 0, 0, 0);
        }

        if (kw + 1 < NCH) {
            u32* dbuf = wt + ((kw + 1) & 1) * (16 * PC);
            #pragma unroll
            for (int j = 0; j < 2; ++j)
                #pragma unroll
                for (int i = 0; i < 4; ++i) {
                    float lo = ((const float*)&wnx[j])[i];
                    float hi = ((const float*)&wnx[2 + j])[i];
                    dbuf[rp * PC + 4 * u + 128 * j + i] = (u32)f2bf(lo) | ((u32)f2bf(hi) << 16);
                }
            #pragma unroll
            for (int rf = 0; rf < 4; ++rf) a[rf] = an[rf];
            __syncthreads();
        }
    }

    // epilogue: bf16 stores. D: col=lane&15, row=(lane>>4)*4+reg
    u16* sp = slabs + (size_t)s * N_ROWS * JK;
    #pragma unroll
    for (int rf = 0; rf < 4; ++rf)
        #pragma unroll
        for (int cf = 0; cf < 8; ++cf)
            #pragma unroll
            for (int rr = 0; rr < 4; ++rr) {
                int row = wr0 + rf * 16 + q * 4 + rr;
                int col = c0 + wc0 + cf * 16 + n;
                sp[(size_t)row * JK + col] = f2bf(acc[rf][cf][rr]);
            }
}

// Kernel C: feats[n,jk] = sum_s slab[s][n,jk] (bf16 -> fp32).
__global__ __launch_bounds__(256) void reduce_kernel(const u16* __restrict__ slabs,
                                                     float* __restrict__ feats)
{
    int t = blockIdx.x * 256 + threadIdx.x;      // 65536 threads x 8 elems
    float acc[8] = {};
    for (int s = 0; s < NSLAB; ++s) {
        uint4 v = *(const uint4*)(slabs + (size_t)s * N_ROWS * JK + (size_t)t * 8);
        const u16* h = (const u16*)&v;
        #pragma unroll
        for (int e = 0; e < 8; ++e) acc[e] += bf2f(h[e]);
    }
    float4* fp = (float4*)(feats + (size_t)t * 8);
    fp[0] = make_float4(acc[0], acc[1], acc[2], acc[3]);
    fp[1] = make_float4(acc[4], acc[5], acc[6], acc[7]);
}

// Kernel D: diversity[n,j] = sum_m exp(-sum_k |feats[n,j,k]-feats[m,j,k]|), m-chunked.
__global__ __launch_bounds__(256) void pairwise_kernel(const float* __restrict__ feats,
                                                       float* __restrict__ out)
{
    const int j = blockIdx.x;              // 0..127
    const int mq = blockIdx.y;             // 0..3 -> m chunk of 64
    const int n = threadIdx.x;

    __shared__ float F[N_ROWS * KDIM];     // 16 KB
    const float* fr = feats + (size_t)n * JK + j * KDIM;
    float4 v0 = ((const float4*)fr)[0];
    float4 v1 = ((const float4*)fr)[1];
    float4 v2 = ((const float4*)fr)[2];
    float4 v3 = ((const float4*)fr)[3];
    float4* Fp = (float4*)&F[n * KDIM];
    Fp[0] = v0; Fp[1] = v1; Fp[2] = v2; Fp[3] = v3;
    __syncthreads();

    float f[16] = { v0.x, v0.y, v0.z, v0.w, v1.x, v1.y, v1.z, v1.w,
                    v2.x, v2.y, v2.z, v2.w, v3.x, v3.y, v3.z, v3.w };
    float accum = 0.f;
    const int m0 = mq * 64;
    for (int m = 0; m < 64; ++m) {
        const float* Fm = &F[(m0 + m) * KDIM];   // wave-uniform -> LDS broadcast
        float l1 = 0.f;
        #pragma unroll
        for (int k = 0; k < 16; ++k) l1 += fabsf(f[k] - Fm[k]);
        accum += exp2f(-1.4426950408889634f * l1);
    }
    atomicAdd(&out[(size_t)n * OUT_F + IN_F + j], accum);
}

extern "C" void kernel_launch(void* const* d_in, const int* in_sizes, int n_in,
                              void* d_out, int out_size, void* d_ws, size_t ws_size,
                              hipStream_t stream)
{
    const float* X = (const float*)d_in[0];   // [256, 8192] fp32
    const float* T = (const float*)d_in[1];   // [8192, 128, 16] fp32 = [8192, 2048]
    float* out = (float*)d_out;               // [256, 8320] fp32

    float* feats = (float*)d_ws;                            // 2 MB fp32 [256,2048]
    u16*   Xb    = (u16*)((char*)d_ws + (2u << 20));        // 4 MB bf16 [256,8192]
    u16*   slabs = (u16*)((char*)d_ws + (6u << 20));        // 32 MB bf16 [32,256,2048]

    prep_kernel<<<2048, 256, 0, stream>>>(X, out, Xb);
    gemm_kernel<<<dim3(JK / BN, NSLAB), 512, 0, stream>>>(Xb, T, slabs);
    reduce_kernel<<<256, 256, 0, stream>>>(slabs, feats);
    pairwise_kernel<<<dim3(JDIM, 4), 256, 0, stream>>>(feats, out);
}